// Round 1
// baseline (378.783 us; speedup 1.0000x reference)
//
#include <hip/hip_runtime.h>

typedef short bf16x8 __attribute__((ext_vector_type(8)));
typedef float f32x4 __attribute__((ext_vector_type(4)));
typedef unsigned short us4v __attribute__((ext_vector_type(4)));

#define DEV static __device__ __forceinline__

DEV float bf2f(unsigned short u){ unsigned int x = ((unsigned int)u)<<16; float f; __builtin_memcpy(&f,&x,4); return f; }
DEV unsigned short f2bf(float f){ unsigned int x; __builtin_memcpy(&x,&f,4); x = (x + 0x7fffu + ((x>>16)&1u)) >> 16; return (unsigned short)x; }

DEV void stor(unsigned short* p, float v){ *p = f2bf(v); }
DEV void stor(float* p, float v){ *p = v; }

#define GLOAD_LDS16(gptr, lptr) \
  __builtin_amdgcn_global_load_lds((__attribute__((address_space(1))) void*)(gptr), \
      (__attribute__((address_space(3))) void*)(lptr), 16, 0, 0)

// C = A[M,K] @ Bt[N,K]^T, bf16 inputs, OutT output. 128x128 tile, BK=32, 4 waves.
template<typename OutT>
__global__ __launch_bounds__(256) void gemm_bt(
    const unsigned short* __restrict__ A,
    const unsigned short* __restrict__ Bt,
    OutT* __restrict__ C, int M, int N, int K)
{
  __shared__ unsigned short As[128*32];
  __shared__ unsigned short Bs[128*32];
  const int tid = threadIdx.x;
  const int w = tid>>6, l = tid&63, g = l>>4, q = l&15;
  const int m0 = blockIdx.x*128, n0 = blockIdx.y*128;
  f32x4 acc[4][4];
  const f32x4 fz = {0.f,0.f,0.f,0.f};
  for (int i=0;i<4;i++) for(int j=0;j<4;j++) acc[i][j] = fz;
  for (int k0 = 0; k0 < K; k0 += 32) {
    __syncthreads();
    #pragma unroll
    for (int r = 0; r < 2; ++r) {
      int p = r*4096 + tid*16;
      int row = p>>6, colb = p&63;
      const char* ga = (const char*)(A  + (size_t)(m0+row)*K + k0) + colb;
      const char* gb = (const char*)(Bt + (size_t)(n0+row)*K + k0) + colb;
      GLOAD_LDS16(ga, (char*)As + r*4096 + w*1024);
      GLOAD_LDS16(gb, (char*)Bs + r*4096 + w*1024);
    }
    __syncthreads();
    bf16x8 af[4], bfr[4];
    #pragma unroll
    for (int i=0;i<4;i++){
      af[i]  = *(const bf16x8*)&As[((w>>1)*64 + i*16 + q)*32 + g*8];
      bfr[i] = *(const bf16x8*)&Bs[((w&1)*64 + i*16 + q)*32 + g*8];
    }
    #pragma unroll
    for (int i=0;i<4;i++)
      #pragma unroll
      for (int j=0;j<4;j++)
        acc[i][j] = __builtin_amdgcn_mfma_f32_16x16x32_bf16(af[i], bfr[j], acc[i][j], 0,0,0);
  }
  #pragma unroll
  for (int i=0;i<4;i++)
    #pragma unroll
    for (int j=0;j<4;j++)
      #pragma unroll
      for (int v=0;v<4;v++){
        int row = m0 + (w>>1)*64 + i*16 + g*4 + v;
        int col = n0 + (w&1)*64 + j*16 + q;
        stor(&C[(size_t)row*N + col], acc[i][j][v]);
      }
}

// Differential flash attention. Q,K: [4096][2048] bf16 (per head: Q1|Q2 / K1|K2).
// Vt: [1024][4096] bf16 (V transposed). aout: [4096][1024] bf16.
__global__ __launch_bounds__(256) void diff_attn(
    const unsigned short* __restrict__ Q,
    const unsigned short* __restrict__ K,
    const unsigned short* __restrict__ Vt,
    const float* __restrict__ lambp,
    unsigned short* __restrict__ aout)
{
  __shared__ unsigned short Ks[64*136];     // 64 keys x 128 d, +8 pad
  __shared__ unsigned short Vs[64*72];      // 64 d x 64 keys, +8 pad
  __shared__ unsigned short P1s[4][16*72];  // per-wave P transpose buffers
  __shared__ unsigned short P2s[4][16*72];
  const int tid = threadIdx.x, w = tid>>6, l = tid&63, g = l>>4, q = l&15;
  const int qb = blockIdx.x, h = blockIdx.y, b = blockIdx.z;
  const int qrow0 = b*2048 + qb*64 + w*16;

  // Q fragments, scaled by 1/8 (exact in bf16)
  bf16x8 q1f[2], q2f[2];
  {
    const unsigned short* qp = Q + (size_t)(qrow0 + q)*2048 + h*128;
    #pragma unroll
    for (int kf=0;kf<2;kf++){
      bf16x8 t1 = *(const bf16x8*)(qp + kf*32 + g*8);
      bf16x8 t2 = *(const bf16x8*)(qp + 64 + kf*32 + g*8);
      #pragma unroll
      for (int e=0;e<8;e++){
        t1[e] = (short)f2bf(bf2f((unsigned short)t1[e]) * 0.125f);
        t2[e] = (short)f2bf(bf2f((unsigned short)t2[e]) * 0.125f);
      }
      q1f[kf]=t1; q2f[kf]=t2;
    }
  }
  float m1[4], m2[4], s1[4], s2[4];
  f32x4 acc1[4], acc2[4];
  const f32x4 fz = {0.f,0.f,0.f,0.f};
  #pragma unroll
  for (int i=0;i<4;i++){ m1[i]=m2[i]=-3e38f; s1[i]=s2[i]=0.f; acc1[i]=fz; acc2[i]=fz; }

  for (int kt=0; kt<2048; kt+=64) {
    __syncthreads();
    { // stage K tile
      int key = tid>>2, c0 = tid&3;
      const unsigned short* src = K + (size_t)(b*2048 + kt + key)*2048 + h*128;
      #pragma unroll
      for (int c=0;c<4;c++){
        int ch = c0 + c*4;
        *(bf16x8*)&Ks[key*136 + ch*8] = *(const bf16x8*)(src + ch*8);
      }
    }
    { // stage V tile (from Vt rows: contiguous keys)
      int d = tid>>2, c0 = tid&3;
      const unsigned short* src = Vt + (size_t)(h*64 + d)*4096 + b*2048 + kt;
      #pragma unroll
      for (int c=0;c<2;c++){
        int ch = c0 + c*4;
        *(bf16x8*)&Vs[d*72 + ch*8] = *(const bf16x8*)(src + ch*8);
      }
    }
    __syncthreads();
    // scores: D[q][key] frags; row=(l>>4)*4+i, col=l&15
    f32x4 sf1[4], sf2[4];
    #pragma unroll
    for (int fn=0; fn<4; ++fn) {
      int krow = (fn*16 + q)*136;
      bf16x8 kb0 = *(const bf16x8*)&Ks[krow + g*8];
      bf16x8 kb1 = *(const bf16x8*)&Ks[krow + 32 + g*8];
      f32x4 z = fz;
      z = __builtin_amdgcn_mfma_f32_16x16x32_bf16(q1f[0], kb0, z, 0,0,0);
      z = __builtin_amdgcn_mfma_f32_16x16x32_bf16(q1f[1], kb1, z, 0,0,0);
      sf1[fn] = z;
      bf16x8 kc0 = *(const bf16x8*)&Ks[krow + 64 + g*8];
      bf16x8 kc1 = *(const bf16x8*)&Ks[krow + 96 + g*8];
      f32x4 z2 = fz;
      z2 = __builtin_amdgcn_mfma_f32_16x16x32_bf16(q2f[0], kc0, z2, 0,0,0);
      z2 = __builtin_amdgcn_mfma_f32_16x16x32_bf16(q2f[1], kc1, z2, 0,0,0);
      sf2[fn] = z2;
    }
    // dual online softmax; rows g*4+i, 16 cols spread over lanes of group g
    #pragma unroll
    for (int i=0;i<4;i++){
      float t1v = fmaxf(fmaxf(sf1[0][i],sf1[1][i]), fmaxf(sf1[2][i],sf1[3][i]));
      float t2v = fmaxf(fmaxf(sf2[0][i],sf2[1][i]), fmaxf(sf2[2][i],sf2[3][i]));
      #pragma unroll
      for (int o=1;o<16;o<<=1){ t1v = fmaxf(t1v, __shfl_xor(t1v,o)); t2v = fmaxf(t2v, __shfl_xor(t2v,o)); }
      float nm1 = fmaxf(m1[i], t1v), nm2 = fmaxf(m2[i], t2v);
      float sc1 = __expf(m1[i]-nm1), sc2 = __expf(m2[i]-nm2);
      float rs1 = 0.f, rs2 = 0.f;
      #pragma unroll
      for (int fn=0;fn<4;fn++){
        float p1 = __expf(sf1[fn][i]-nm1); rs1 += p1;
        float p2 = __expf(sf2[fn][i]-nm2); rs2 += p2;
        P1s[w][(g*4+i)*72 + fn*16 + q] = f2bf(p1);
        P2s[w][(g*4+i)*72 + fn*16 + q] = f2bf(p2);
      }
      #pragma unroll
      for (int o=1;o<16;o<<=1){ rs1 += __shfl_xor(rs1,o); rs2 += __shfl_xor(rs2,o); }
      s1[i] = s1[i]*sc1 + rs1; s2[i] = s2[i]*sc2 + rs2;
      m1[i]=nm1; m2[i]=nm2;
      #pragma unroll
      for (int fd=0;fd<4;fd++){ acc1[fd][i]*=sc1; acc2[fd][i]*=sc2; }
    }
    // PV: A = P[q 16][k], B = V (col=d, contraction=key)
    #pragma unroll
    for (int kh=0; kh<2; ++kh) {
      bf16x8 pa1 = *(const bf16x8*)&P1s[w][q*72 + kh*32 + g*8];
      bf16x8 pa2 = *(const bf16x8*)&P2s[w][q*72 + kh*32 + g*8];
      #pragma unroll
      for (int fd=0; fd<4; ++fd) {
        bf16x8 vb = *(const bf16x8*)&Vs[(fd*16+q)*72 + kh*32 + g*8];
        acc1[fd] = __builtin_amdgcn_mfma_f32_16x16x32_bf16(pa1, vb, acc1[fd], 0,0,0);
        acc2[fd] = __builtin_amdgcn_mfma_f32_16x16x32_bf16(pa2, vb, acc2[fd], 0,0,0);
      }
    }
  }
  float lamb = lambp[0];
  #pragma unroll
  for (int fd=0; fd<4; ++fd)
    #pragma unroll
    for (int i=0;i<4;i++){
      float val = acc1[fd][i]/s1[i] - lamb*(acc2[fd][i]/s2[i]);
      int row = qrow0 + g*4 + i;
      int col = h*64 + fd*16 + q;
      aout[(size_t)row*1024 + col] = f2bf(val);
    }
}

__global__ __launch_bounds__(256) void f32_to_bf16_k(const float* __restrict__ in, unsigned short* __restrict__ out, int n){
  int i = (blockIdx.x*256 + threadIdx.x)*4;
  if (i >= n) return;
  float4 vv = *(const float4*)(in + i);
  us4v o; o[0]=f2bf(vv.x); o[1]=f2bf(vv.y); o[2]=f2bf(vv.z); o[3]=f2bf(vv.w);
  *(us4v*)(out + i) = o;
}

// in: [R][C] f32 -> out: [C][R] bf16
__global__ void transpose_f32_bf16(const float* __restrict__ in, unsigned short* __restrict__ out, int R, int C){
  __shared__ unsigned short t[32][33];
  int c0 = blockIdx.x*32, r0 = blockIdx.y*32;
  int x = threadIdx.x, y = threadIdx.y;
  #pragma unroll
  for (int d=0; d<32; d+=8) t[y+d][x] = f2bf(in[(size_t)(r0+y+d)*C + c0 + x]);
  __syncthreads();
  #pragma unroll
  for (int d=0; d<32; d+=8) out[(size_t)(c0+y+d)*R + r0 + x] = t[x][y+d];
}

// in: [R][C] bf16 -> out: [C][R] bf16
__global__ void transpose_bf16(const unsigned short* __restrict__ in, unsigned short* __restrict__ out, int R, int C){
  __shared__ unsigned short t[32][33];
  int c0 = blockIdx.x*32, r0 = blockIdx.y*32;
  int x = threadIdx.x, y = threadIdx.y;
  #pragma unroll
  for (int d=0; d<32; d+=8) t[y+d][x] = in[(size_t)(r0+y+d)*C + c0 + x];
  __syncthreads();
  #pragma unroll
  for (int d=0; d<32; d+=8) out[(size_t)(c0+y+d)*R + r0 + x] = t[x][y+d];
}

__global__ void lamb_k(const float* lq1, const float* lk1, const float* lq2, const float* lk2, float* out){
  int i = threadIdx.x;
  float a = lq1[i]*lk1[i], c = lq2[i]*lk2[i];
  #pragma unroll
  for (int o=32;o>0;o>>=1){ a += __shfl_down(a,o); c += __shfl_down(c,o); }
  if (i==0) out[0] = expf(a) - expf(c) + 0.7778700995592560f; // LAMBDA_INIT for layer 12
}

__global__ __launch_bounds__(256) void ln_k(const float* __restrict__ in, const float* __restrict__ gam,
                                            const float* __restrict__ bet, float* __restrict__ out){
  int row = blockIdx.x, t = threadIdx.x;
  const float4* rp = (const float4*)(in + (size_t)row*1024);
  float4 v4 = rp[t];
  float s = v4.x+v4.y+v4.z+v4.w;
  float ss = v4.x*v4.x+v4.y*v4.y+v4.z*v4.z+v4.w*v4.w;
  #pragma unroll
  for (int o=1;o<64;o<<=1){ s += __shfl_xor(s,o); ss += __shfl_xor(ss,o); }
  __shared__ float red[8];
  int w = t>>6, l = t&63;
  if (l==0){ red[w]=s; red[4+w]=ss; }
  __syncthreads();
  s = red[0]+red[1]+red[2]+red[3];
  ss = red[4]+red[5]+red[6]+red[7];
  float mean = s*(1.0f/1024.0f);
  float var = ss*(1.0f/1024.0f) - mean*mean;
  float rstd = rsqrtf(var + 1e-5f);
  float4 gv = ((const float4*)gam)[t], bv = ((const float4*)bet)[t];
  float4 o;
  o.x = (v4.x-mean)*rstd*gv.x + bv.x;
  o.y = (v4.y-mean)*rstd*gv.y + bv.y;
  o.z = (v4.z-mean)*rstd*gv.z + bv.z;
  o.w = (v4.w-mean)*rstd*gv.w + bv.w;
  ((float4*)(out + (size_t)row*1024))[t] = o;
}

extern "C" void kernel_launch(void* const* d_in, const int* in_sizes, int n_in,
                              void* d_out, int out_size, void* d_ws, size_t ws_size,
                              hipStream_t stream) {
  const float* x     = (const float*)d_in[0];
  const float* Wq    = (const float*)d_in[1];
  const float* Wk    = (const float*)d_in[2];
  const float* Wv    = (const float*)d_in[3];
  const float* Wo    = (const float*)d_in[4];
  const float* lq1   = (const float*)d_in[5];
  const float* lk1   = (const float*)d_in[6];
  const float* lq2   = (const float*)d_in[7];
  const float* lk2   = (const float*)d_in[8];
  const float* gamma = (const float*)d_in[9];
  const float* beta  = (const float*)d_in[10];
  float* out = (float*)d_out;

  char* ws = (char*)d_ws;
  unsigned short* xb   = (unsigned short*)(ws);                    //  8,388,608 B
  unsigned short* WqT  = (unsigned short*)(ws + 8388608);          //  4,194,304
  unsigned short* WkT  = (unsigned short*)(ws + 12582912);         //  4,194,304
  unsigned short* WvT  = (unsigned short*)(ws + 16777216);         //  2,097,152
  unsigned short* WoT  = (unsigned short*)(ws + 18874368);         //  2,097,152
  unsigned short* Qb   = (unsigned short*)(ws + 20971520);         // 16,777,216
  unsigned short* Kb   = (unsigned short*)(ws + 37748736);         // 16,777,216
  unsigned short* Vb   = (unsigned short*)(ws + 54525952);         //  8,388,608
  unsigned short* Vtb  = (unsigned short*)(ws + 62914560);         //  8,388,608
  unsigned short* AOb  = (unsigned short*)(ws + 71303168);         //  8,388,608
  float*          proj = (float*)(ws + 79691776);                  // 16,777,216
  float*          lambp= (float*)(ws + 96468992);                  //  4

  dim3 tb(32,8);
  f32_to_bf16_k<<<4096, 256, 0, stream>>>(x, xb, 4194304);
  transpose_f32_bf16<<<dim3(64,32), tb, 0, stream>>>(Wq, WqT, 1024, 2048);
  transpose_f32_bf16<<<dim3(64,32), tb, 0, stream>>>(Wk, WkT, 1024, 2048);
  transpose_f32_bf16<<<dim3(32,32), tb, 0, stream>>>(Wv, WvT, 1024, 1024);
  transpose_f32_bf16<<<dim3(32,32), tb, 0, stream>>>(Wo, WoT, 1024, 1024);
  lamb_k<<<1, 64, 0, stream>>>(lq1, lk1, lq2, lk2, lambp);

  gemm_bt<unsigned short><<<dim3(32,16), 256, 0, stream>>>(xb, WqT, Qb, 4096, 2048, 1024);
  gemm_bt<unsigned short><<<dim3(32,16), 256, 0, stream>>>(xb, WkT, Kb, 4096, 2048, 1024);
  gemm_bt<unsigned short><<<dim3(32,8),  256, 0, stream>>>(xb, WvT, Vb, 4096, 1024, 1024);
  transpose_bf16<<<dim3(32,128), tb, 0, stream>>>(Vb, Vtb, 4096, 1024);

  diff_attn<<<dim3(32,16,2), 256, 0, stream>>>(Qb, Kb, Vtb, lambp, AOb);

  gemm_bt<float><<<dim3(32,8), 256, 0, stream>>>(AOb, WoT, proj, 4096, 1024, 1024);
  ln_k<<<4096, 256, 0, stream>>>(proj, gamma, beta, out);
}

// Round 2
// 313.251 us; speedup vs baseline: 1.2092x; 1.2092x over previous
//
#include <hip/hip_runtime.h>
#include <hip/hip_bf16.h>

typedef short bf16x8 __attribute__((ext_vector_type(8)));
typedef float f32x4 __attribute__((ext_vector_type(4)));
typedef unsigned short us4v __attribute__((ext_vector_type(4)));

#define DEV static __device__ __forceinline__

DEV float bf2f(unsigned short u){ unsigned int x = ((unsigned int)u)<<16; float f; __builtin_memcpy(&f,&x,4); return f; }
DEV unsigned short f2bf(float f){ unsigned int x; __builtin_memcpy(&x,&f,4); x = (x + 0x7fffu + ((x>>16)&1u)) >> 16; return (unsigned short)x; }
DEV unsigned int pack_bf16x2(float lo, float hi){
  __hip_bfloat162 h = __float22bfloat162_rn(float2{lo, hi});
  unsigned int u; __builtin_memcpy(&u, &h, 4); return u;
}

DEV void stor(unsigned short* p, float v){ *p = f2bf(v); }
DEV void stor(float* p, float v){ *p = v; }

#define GLOAD_LDS16(gptr, lptr) \
  __builtin_amdgcn_global_load_lds((__attribute__((address_space(1))) void*)(gptr), \
      (__attribute__((address_space(3))) void*)(lptr), 16, 0, 0)

// C = A[M,K] @ Bt[N,K]^T, bf16 inputs, OutT output. 128x128 tile, BK=32, 4 waves.
template<typename OutT>
__global__ __launch_bounds__(256) void gemm_bt(
    const unsigned short* __restrict__ A,
    const unsigned short* __restrict__ Bt,
    OutT* __restrict__ C, int M, int N, int K)
{
  __shared__ unsigned short As[128*32];
  __shared__ unsigned short Bs[128*32];
  const int tid = threadIdx.x;
  const int w = tid>>6, l = tid&63, g = l>>4, q = l&15;
  const int m0 = blockIdx.x*128, n0 = blockIdx.y*128;
  f32x4 acc[4][4];
  const f32x4 fz = {0.f,0.f,0.f,0.f};
  for (int i=0;i<4;i++) for(int j=0;j<4;j++) acc[i][j] = fz;
  for (int k0 = 0; k0 < K; k0 += 32) {
    __syncthreads();
    #pragma unroll
    for (int r = 0; r < 2; ++r) {
      int p = r*4096 + tid*16;
      int row = p>>6, colb = p&63;
      const char* ga = (const char*)(A  + (size_t)(m0+row)*K + k0) + colb;
      const char* gb = (const char*)(Bt + (size_t)(n0+row)*K + k0) + colb;
      GLOAD_LDS16(ga, (char*)As + r*4096 + w*1024);
      GLOAD_LDS16(gb, (char*)Bs + r*4096 + w*1024);
    }
    __syncthreads();
    bf16x8 af[4], bfr[4];
    #pragma unroll
    for (int i=0;i<4;i++){
      af[i]  = *(const bf16x8*)&As[((w>>1)*64 + i*16 + q)*32 + g*8];
      bfr[i] = *(const bf16x8*)&Bs[((w&1)*64 + i*16 + q)*32 + g*8];
    }
    #pragma unroll
    for (int i=0;i<4;i++)
      #pragma unroll
      for (int j=0;j<4;j++)
        acc[i][j] = __builtin_amdgcn_mfma_f32_16x16x32_bf16(af[i], bfr[j], acc[i][j], 0,0,0);
  }
  #pragma unroll
  for (int i=0;i<4;i++)
    #pragma unroll
    for (int j=0;j<4;j++)
      #pragma unroll
      for (int v=0;v<4;v++){
        int row = m0 + (w>>1)*64 + i*16 + g*4 + v;
        int col = n0 + (w&1)*64 + j*16 + q;
        stor(&C[(size_t)row*N + col], acc[i][j][v]);
      }
}

// Differential flash attention, static-max dual softmax.
// Q,K: [4096][2048] bf16 (per head: Q1|Q2 / K1|K2). Vt: [1024][4096] bf16.
// aout: [4096][1024] bf16.
// LDS: Ks [64][128] XOR-swizzled (granule ^= row&7), Vs [64][64] swizzled,
// P12 per-wave [16][64] u32 (bf16 p1 | p2<<16) swizzled. Total 40960 B.
__global__ __launch_bounds__(256,4) void diff_attn(
    const unsigned short* __restrict__ Q,
    const unsigned short* __restrict__ K,
    const unsigned short* __restrict__ Vt,
    const float* __restrict__ lambp,
    unsigned short* __restrict__ aout)
{
  __shared__ unsigned short Ks[64*128];   // 16 KiB
  __shared__ unsigned short Vs[64*64];    //  8 KiB
  __shared__ unsigned int  P12[4][16*64]; // 16 KiB
  const int tid = threadIdx.x, w = tid>>6, l = tid&63, g = l>>4, q = l&15;
  const int qb = blockIdx.x, h = blockIdx.y, b = blockIdx.z;
  const int qrow0 = b*2048 + qb*64 + w*16;

  // Q fragments, scaled by 1/8 (exact in bf16)
  bf16x8 q1f[2], q2f[2];
  {
    const unsigned short* qp = Q + (size_t)(qrow0 + q)*2048 + h*128;
    #pragma unroll
    for (int kf=0;kf<2;kf++){
      bf16x8 t1 = *(const bf16x8*)(qp + kf*32 + g*8);
      bf16x8 t2 = *(const bf16x8*)(qp + 64 + kf*32 + g*8);
      #pragma unroll
      for (int e=0;e<8;e++){
        t1[e] = (short)f2bf(bf2f((unsigned short)t1[e]) * 0.125f);
        t2[e] = (short)f2bf(bf2f((unsigned short)t2[e]) * 0.125f);
      }
      q1f[kf]=t1; q2f[kf]=t2;
    }
  }
  float s1[4], s2[4];
  f32x4 acc1[4], acc2[4];
  const f32x4 fz = {0.f,0.f,0.f,0.f};
  #pragma unroll
  for (int i=0;i<4;i++){ s1[i]=0.f; s2[i]=0.f; acc1[i]=fz; acc2[i]=fz; }

  const int rowl = tid & 63;
  const int swl = rowl & 7;
  const unsigned short* srcK0 = K + (size_t)(b*2048 + rowl)*2048 + h*128;
  const unsigned short* srcV0 = Vt + (size_t)(h*64 + rowl)*4096 + b*2048;

  for (int kt=0; kt<2048; kt+=64) {
    __syncthreads();
    { // stage K tile: row rowl, 16B granules ch = w+4c, swizzled granule = ch^swl
      const unsigned short* srcK = srcK0 + (size_t)kt*2048;
      #pragma unroll
      for (int c=0;c<4;c++){
        int ch = w + c*4;
        *(bf16x8*)&Ks[rowl*128 + (ch^swl)*8] = *(const bf16x8*)(srcK + ch*8);
      }
      const unsigned short* srcV = srcV0 + kt;
      #pragma unroll
      for (int c=0;c<2;c++){
        int ch = w + c*4;
        *(bf16x8*)&Vs[rowl*64 + (ch^swl)*8] = *(const bf16x8*)(srcV + ch*8);
      }
    }
    __syncthreads();
    // scores + softmax, fn-by-fn (keeps VGPR low, interleaves MFMA/VALU)
    const int sw = q & 7;
    #pragma unroll
    for (int fn=0; fn<4; ++fn) {
      int krow = fn*16 + q;
      bf16x8 kb0 = *(const bf16x8*)&Ks[krow*128 + ((0*4+g)^sw)*8];
      bf16x8 kb1 = *(const bf16x8*)&Ks[krow*128 + ((1*4+g)^sw)*8];
      bf16x8 kc0 = *(const bf16x8*)&Ks[krow*128 + ((2*4+g)^sw)*8];
      bf16x8 kc1 = *(const bf16x8*)&Ks[krow*128 + ((3*4+g)^sw)*8];
      f32x4 z = fz, z2 = fz;
      z  = __builtin_amdgcn_mfma_f32_16x16x32_bf16(q1f[0], kb0, z, 0,0,0);
      z  = __builtin_amdgcn_mfma_f32_16x16x32_bf16(q1f[1], kb1, z, 0,0,0);
      z2 = __builtin_amdgcn_mfma_f32_16x16x32_bf16(q2f[0], kc0, z2, 0,0,0);
      z2 = __builtin_amdgcn_mfma_f32_16x16x32_bf16(q2f[1], kc1, z2, 0,0,0);
      #pragma unroll
      for (int i=0;i<4;i++){
        float p1 = __expf(z[i]);
        float p2 = __expf(z2[i]);
        unsigned int pk = pack_bf16x2(p1, p2);
        int row = g*4+i;
        P12[w][row*64 + (((fn*4 + (q>>2)) ^ (row&7))<<2) + (q&3)] = pk;
        s1[i] += bf2f((unsigned short)pk);
        s2[i] += bf2f((unsigned short)(pk>>16));
      }
    }
    // PV: A = P[q][key] (de-interleaved), B = V^T[d][key]
    #pragma unroll
    for (int kh=0; kh<2; ++kh) {
      int g0 = (kh*8 + g*2)     ^ sw;
      int g1 = (kh*8 + g*2 + 1) ^ sw;
      uint4 r0 = *(const uint4*)&P12[w][q*64 + g0*4];
      uint4 r1 = *(const uint4*)&P12[w][q*64 + g1*4];
      bf16x8 pa1, pa2;
      unsigned int* a1 = (unsigned int*)&pa1;
      unsigned int* a2 = (unsigned int*)&pa2;
      a1[0] = (r0.x & 0xffffu) | (r0.y << 16);
      a2[0] = (r0.x >> 16)     | (r0.y & 0xffff0000u);
      a1[1] = (r0.z & 0xffffu) | (r0.w << 16);
      a2[1] = (r0.z >> 16)     | (r0.w & 0xffff0000u);
      a1[2] = (r1.x & 0xffffu) | (r1.y << 16);
      a2[2] = (r1.x >> 16)     | (r1.y & 0xffff0000u);
      a1[3] = (r1.z & 0xffffu) | (r1.w << 16);
      a2[3] = (r1.z >> 16)     | (r1.w & 0xffff0000u);
      #pragma unroll
      for (int fd=0; fd<4; ++fd) {
        int vrow = fd*16 + q;
        bf16x8 vb = *(const bf16x8*)&Vs[vrow*64 + ((kh*4+g)^sw)*8];
        acc1[fd] = __builtin_amdgcn_mfma_f32_16x16x32_bf16(pa1, vb, acc1[fd], 0,0,0);
        acc2[fd] = __builtin_amdgcn_mfma_f32_16x16x32_bf16(pa2, vb, acc2[fd], 0,0,0);
      }
    }
  }
  // final row sums (keys spread over the 16 q-lanes of this g-group)
  #pragma unroll
  for (int i=0;i<4;i++){
    #pragma unroll
    for (int o=1;o<16;o<<=1){ s1[i] += __shfl_xor(s1[i],o); s2[i] += __shfl_xor(s2[i],o); }
  }
  float lamb = lambp[0];
  float inv1[4], inv2[4];
  #pragma unroll
  for (int i=0;i<4;i++){ inv1[i] = 1.0f/s1[i]; inv2[i] = lamb/s2[i]; }
  #pragma unroll
  for (int fd=0; fd<4; ++fd)
    #pragma unroll
    for (int i=0;i<4;i++){
      float val = acc1[fd][i]*inv1[i] - acc2[fd][i]*inv2[i];
      int row = qrow0 + g*4 + i;
      int col = h*64 + fd*16 + q;
      aout[(size_t)row*1024 + col] = f2bf(val);
    }
}

__global__ __launch_bounds__(256) void f32_to_bf16_k(const float* __restrict__ in, unsigned short* __restrict__ out, int n){
  int i = (blockIdx.x*256 + threadIdx.x)*4;
  if (i >= n) return;
  float4 vv = *(const float4*)(in + i);
  us4v o; o[0]=f2bf(vv.x); o[1]=f2bf(vv.y); o[2]=f2bf(vv.z); o[3]=f2bf(vv.w);
  *(us4v*)(out + i) = o;
}

// in: [R][C] f32 -> out: [C][R] bf16
__global__ void transpose_f32_bf16(const float* __restrict__ in, unsigned short* __restrict__ out, int R, int C){
  __shared__ unsigned short t[32][33];
  int c0 = blockIdx.x*32, r0 = blockIdx.y*32;
  int x = threadIdx.x, y = threadIdx.y;
  #pragma unroll
  for (int d=0; d<32; d+=8) t[y+d][x] = f2bf(in[(size_t)(r0+y+d)*C + c0 + x]);
  __syncthreads();
  #pragma unroll
  for (int d=0; d<32; d+=8) out[(size_t)(c0+y+d)*R + r0 + x] = t[x][y+d];
}

// in: [R][C] bf16 -> out: [C][R] bf16
__global__ void transpose_bf16(const unsigned short* __restrict__ in, unsigned short* __restrict__ out, int R, int C){
  __shared__ unsigned short t[32][33];
  int c0 = blockIdx.x*32, r0 = blockIdx.y*32;
  int x = threadIdx.x, y = threadIdx.y;
  #pragma unroll
  for (int d=0; d<32; d+=8) t[y+d][x] = in[(size_t)(r0+y+d)*C + c0 + x];
  __syncthreads();
  #pragma unroll
  for (int d=0; d<32; d+=8) out[(size_t)(c0+y+d)*R + r0 + x] = t[x][y+d];
}

__global__ void lamb_k(const float* lq1, const float* lk1, const float* lq2, const float* lk2, float* out){
  int i = threadIdx.x;
  float a = lq1[i]*lk1[i], c = lq2[i]*lk2[i];
  #pragma unroll
  for (int o=32;o>0;o>>=1){ a += __shfl_down(a,o); c += __shfl_down(c,o); }
  if (i==0) out[0] = expf(a) - expf(c) + 0.7778700995592560f; // LAMBDA_INIT for layer 12
}

__global__ __launch_bounds__(256) void ln_k(const float* __restrict__ in, const float* __restrict__ gam,
                                            const float* __restrict__ bet, float* __restrict__ out){
  int row = blockIdx.x, t = threadIdx.x;
  const float4* rp = (const float4*)(in + (size_t)row*1024);
  float4 v4 = rp[t];
  float s = v4.x+v4.y+v4.z+v4.w;
  float ss = v4.x*v4.x+v4.y*v4.y+v4.z*v4.z+v4.w*v4.w;
  #pragma unroll
  for (int o=1;o<64;o<<=1){ s += __shfl_xor(s,o); ss += __shfl_xor(ss,o); }
  __shared__ float red[8];
  int w = t>>6, l = t&63;
  if (l==0){ red[w]=s; red[4+w]=ss; }
  __syncthreads();
  s = red[0]+red[1]+red[2]+red[3];
  ss = red[4]+red[5]+red[6]+red[7];
  float mean = s*(1.0f/1024.0f);
  float var = ss*(1.0f/1024.0f) - mean*mean;
  float rstd = rsqrtf(var + 1e-5f);
  float4 gv = ((const float4*)gam)[t], bv = ((const float4*)bet)[t];
  float4 o;
  o.x = (v4.x-mean)*rstd*gv.x + bv.x;
  o.y = (v4.y-mean)*rstd*gv.y + bv.y;
  o.z = (v4.z-mean)*rstd*gv.z + bv.z;
  o.w = (v4.w-mean)*rstd*gv.w + bv.w;
  ((float4*)(out + (size_t)row*1024))[t] = o;
}

extern "C" void kernel_launch(void* const* d_in, const int* in_sizes, int n_in,
                              void* d_out, int out_size, void* d_ws, size_t ws_size,
                              hipStream_t stream) {
  const float* x     = (const float*)d_in[0];
  const float* Wq    = (const float*)d_in[1];
  const float* Wk    = (const float*)d_in[2];
  const float* Wv    = (const float*)d_in[3];
  const float* Wo    = (const float*)d_in[4];
  const float* lq1   = (const float*)d_in[5];
  const float* lk1   = (const float*)d_in[6];
  const float* lq2   = (const float*)d_in[7];
  const float* lk2   = (const float*)d_in[8];
  const float* gamma = (const float*)d_in[9];
  const float* beta  = (const float*)d_in[10];
  float* out = (float*)d_out;

  char* ws = (char*)d_ws;
  unsigned short* xb   = (unsigned short*)(ws);                    //  8,388,608 B
  unsigned short* WqT  = (unsigned short*)(ws + 8388608);          //  4,194,304
  unsigned short* WkT  = (unsigned short*)(ws + 12582912);         //  4,194,304
  unsigned short* WvT  = (unsigned short*)(ws + 16777216);         //  2,097,152
  unsigned short* WoT  = (unsigned short*)(ws + 18874368);         //  2,097,152
  unsigned short* Qb   = (unsigned short*)(ws + 20971520);         // 16,777,216
  unsigned short* Kb   = (unsigned short*)(ws + 37748736);         // 16,777,216
  unsigned short* Vb   = (unsigned short*)(ws + 54525952);         //  8,388,608
  unsigned short* Vtb  = (unsigned short*)(ws + 62914560);         //  8,388,608
  unsigned short* AOb  = (unsigned short*)(ws + 71303168);         //  8,388,608
  float*          proj = (float*)(ws + 79691776);                  // 16,777,216
  float*          lambp= (float*)(ws + 96468992);                  //  4

  dim3 tb(32,8);
  f32_to_bf16_k<<<4096, 256, 0, stream>>>(x, xb, 4194304);
  transpose_f32_bf16<<<dim3(64,32), tb, 0, stream>>>(Wq, WqT, 1024, 2048);
  transpose_f32_bf16<<<dim3(64,32), tb, 0, stream>>>(Wk, WkT, 1024, 2048);
  transpose_f32_bf16<<<dim3(32,32), tb, 0, stream>>>(Wv, WvT, 1024, 1024);
  transpose_f32_bf16<<<dim3(32,32), tb, 0, stream>>>(Wo, WoT, 1024, 1024);
  lamb_k<<<1, 64, 0, stream>>>(lq1, lk1, lq2, lk2, lambp);

  gemm_bt<unsigned short><<<dim3(32,16), 256, 0, stream>>>(xb, WqT, Qb, 4096, 2048, 1024);
  gemm_bt<unsigned short><<<dim3(32,16), 256, 0, stream>>>(xb, WkT, Kb, 4096, 2048, 1024);
  gemm_bt<unsigned short><<<dim3(32,8),  256, 0, stream>>>(xb, WvT, Vb, 4096, 1024, 1024);
  transpose_bf16<<<dim3(32,128), tb, 0, stream>>>(Vb, Vtb, 4096, 1024);

  diff_attn<<<dim3(32,16,2), 256, 0, stream>>>(Qb, Kb, Vtb, lambp, AOb);

  gemm_bt<float><<<dim3(32,8), 256, 0, stream>>>(AOb, WoT, proj, 4096, 1024, 1024);
  ln_k<<<4096, 256, 0, stream>>>(proj, gamma, beta, out);
}